// Round 2
// baseline (247.531 us; speedup 1.0000x reference)
//
#include <hip/hip_runtime.h>
#include <stdint.h>

// ---------------- 5G LDPC BG1 encoder, bit-packed GF(2) pipeline ----------------
// Geometry (fixed by the reference problem):
#define Zc      384
#define K_INFO  8000
#define N_OUT   16000
#define K_LDPC  8448        // 22*Z
#define M_A     1536        // 4*Z core parity
#define PB_USED 7232        // pb rows >= 7232 never reach the rate-matched output
#define WPR     64          // uint32 words per packed row (2048 batch bits)
#define BATCH   2048

// Workspace layout (bytes, 256-aligned):
//   u_pack [8448][64] u32 row-major    @ 0
//   uT     [64][8448] u32 word-major   @ 2,162,688
//   au     [1536][64] u32 row-major    @ 4,325,376
//   pa     [1536][64] u32 row-major    @ 4,718,592
//   paT    [64][1536] u32 word-major   @ 5,111,808
//   pbT    [64][7232] u32 word-major   @ 5,505,024
// total 7,356,416 B

__device__ __forceinline__ int lb(const int* __restrict__ a, int n, int key) {
  int lo = 0, hi = n;
  while (lo < hi) {
    int mid = (lo + hi) >> 1;
    if (a[mid] < key) lo = mid + 1; else hi = mid;
  }
  return lo;
}

// K1: pack u (float 0/1, [2048][8000]) into bit-planes. 64x64 tile via LDS +
// __ballot (wave=64). Filler rows 8000..8447 are written as zeros.
__global__ __launch_bounds__(256) void k_pack(const float* __restrict__ u,
                                              uint32_t* __restrict__ u_pack,
                                              uint32_t* __restrict__ uT) {
  __shared__ float tile[64][65];      // [batch][bit], padded
  __shared__ uint64_t bw[64];
  const int k0 = blockIdx.x * 64;
  const int b0 = blockIdx.y * 64;
  const int tid = threadIdx.x;

  #pragma unroll
  for (int i = 0; i < 16; ++i) {
    int lin = tid + i * 256;
    int bb = lin >> 6, kk = lin & 63;
    int k = k0 + kk;
    float v = 0.0f;
    if (k < K_INFO) v = u[(size_t)(b0 + bb) * K_INFO + k];   // coalesced along k
    tile[bb][kk] = v;
  }
  __syncthreads();

  const int lane = tid & 63;
  const int wv   = tid >> 6;
  #pragma unroll
  for (int kk = 0; kk < 16; ++kk) {
    int kp = wv * 16 + kk;
    uint64_t m = __ballot(tile[lane][kp] != 0.0f);  // bit i = batch b0+i
    if (lane == 0) bw[kp] = m;
  }
  __syncthreads();

  if (tid < 64) {
    int row = k0 + tid;
    ((uint64_t*)(u_pack + (size_t)row * WPR))[blockIdx.y] = bw[tid];
  }
  if (tid < 128) {
    int half = tid >> 6, kk = tid & 63;
    uT[(size_t)(2 * blockIdx.y + half) * K_LDPC + k0 + kk] =
        (uint32_t)(bw[kk] >> (32 * half));
  }
}

// Generic bit-packed GF(2) SpMV: dst[r] = XOR_{e: rows[e]==r} src[cols[e]].
// One wave per output row; lane = batch word; 256B coalesced row gathers.
// Optionally also writes a word-major transpose (dstT[lane][r], stride mT).
__global__ __launch_bounds__(256) void k_gf2(const int* __restrict__ rows,
                                             const int* __restrict__ cols, int nnz,
                                             const uint32_t* __restrict__ src,
                                             uint32_t* __restrict__ dst,
                                             uint32_t* __restrict__ dstT, int mT,
                                             int m) {
  const int r = blockIdx.x * 4 + (threadIdx.x >> 6);
  const int lane = threadIdx.x & 63;
  if (r >= m) return;
  const int lo = lb(rows, nnz, r);
  const int hi = lb(rows, nnz, r + 1);
  uint32_t acc = 0;
  for (int e = lo; e < hi; ++e)
    acc ^= src[(size_t)cols[e] * WPR + lane];
  dst[(size_t)r * WPR + lane] = acc;
  if (dstT) dstT[(size_t)lane * mT + r] = acc;
}

// K2b: extension parity rows 0..PB_USED-1: pb = C1*u ^ C2*pa.
__global__ __launch_bounds__(256) void k_ext(const int* __restrict__ c1_rows,
                                             const int* __restrict__ c1_cols, int nc1,
                                             const int* __restrict__ c2_rows,
                                             const int* __restrict__ c2_cols, int nc2,
                                             const uint32_t* __restrict__ u_pack,
                                             const uint32_t* __restrict__ pa,
                                             uint32_t* __restrict__ pbT) {
  const int r = blockIdx.x * 4 + (threadIdx.x >> 6);
  const int lane = threadIdx.x & 63;
  if (r >= PB_USED) return;

  uint32_t acc = 0;
  int lo = lb(c1_rows, nc1, r), hi = lb(c1_rows, nc1, r + 1);
  for (int e = lo; e < hi; ++e)
    acc ^= u_pack[(size_t)c1_cols[e] * WPR + lane];
  lo = lb(c2_rows, nc2, r); hi = lb(c2_rows, nc2, r + 1);
  for (int e = lo; e < hi; ++e)
    acc ^= pa[(size_t)c2_cols[e] * WPR + lane];

  pbT[(size_t)lane * PB_USED + r] = acc;       // scattered 4B stores, 1.85MB total
}

// K3: out[b][4t+j] = c_nf[768 + out_int[4t+j]][b], decoded per region:
//   row<8000 -> u; row<9536 -> pa(row-8000); else pb(row-9536).
// With the actual interleaver (out_int[4t+j]=j*4000+t) all loads are coalesced
// along t from the word-major bit-plane arrays; store is one float4.
__global__ __launch_bounds__(256) void k_out(const uint32_t* __restrict__ uT,
                                             const uint32_t* __restrict__ paT,
                                             const uint32_t* __restrict__ pbT,
                                             const int* __restrict__ out_int,
                                             float* __restrict__ out) {
  const int t = blockIdx.x * 256 + threadIdx.x;
  if (t >= N_OUT / 4) return;
  const int b = blockIdx.y;
  const int w = b >> 5, bit = b & 31;

  const uint32_t* bu = uT  + (size_t)w * K_LDPC;
  const uint32_t* bp = paT + (size_t)w * M_A;
  const uint32_t* bq = pbT + (size_t)w * PB_USED;

  const int4 oi = *(const int4*)(out_int + 4 * t);

  float o[4];
  int rr[4] = {oi.x, oi.y, oi.z, oi.w};
  #pragma unroll
  for (int j = 0; j < 4; ++j) {
    int row = 768 + rr[j];
    uint32_t wv;
    if (row < 8000)       wv = bu[row];
    else if (row < 9536)  wv = bp[row - 8000];
    else                  wv = bq[row - 9536];
    o[j] = (float)((wv >> bit) & 1u);
  }
  float4 v = {o[0], o[1], o[2], o[3]};
  *(float4*)(out + (size_t)b * N_OUT + 4 * t) = v;
}

extern "C" void kernel_launch(void* const* d_in, const int* in_sizes, int n_in,
                              void* d_out, int out_size, void* d_ws, size_t ws_size,
                              hipStream_t stream) {
  const float* u      = (const float*)d_in[0];
  const int* a_rows   = (const int*)d_in[1];
  const int* a_cols   = (const int*)d_in[2];
  const int* bi_rows  = (const int*)d_in[3];
  const int* bi_cols  = (const int*)d_in[4];
  const int* c1_rows  = (const int*)d_in[5];
  const int* c1_cols  = (const int*)d_in[6];
  const int* c2_rows  = (const int*)d_in[7];
  const int* c2_cols  = (const int*)d_in[8];
  const int* out_int  = (const int*)d_in[9];
  const int na  = in_sizes[1];
  const int nbi = in_sizes[3];
  const int nc1 = in_sizes[5];
  const int nc2 = in_sizes[7];

  char* ws = (char*)d_ws;
  uint32_t* u_pack = (uint32_t*)(ws + 0);
  uint32_t* uT     = (uint32_t*)(ws + 2162688);
  uint32_t* au     = (uint32_t*)(ws + 4325376);
  uint32_t* pa     = (uint32_t*)(ws + 4718592);
  uint32_t* paT    = (uint32_t*)(ws + 5111808);
  uint32_t* pbT    = (uint32_t*)(ws + 5505024);
  float* out = (float*)d_out;

  k_pack<<<dim3(K_LDPC / 64, BATCH / 64), 256, 0, stream>>>(u, u_pack, uT);
  // au = A * u
  k_gf2<<<dim3(M_A / 4), 256, 0, stream>>>(a_rows, a_cols, na, u_pack,
                                           au, (uint32_t*)nullptr, 0, M_A);
  // pa = B^-1 * au  (also emit word-major transpose for K3)
  k_gf2<<<dim3(M_A / 4), 256, 0, stream>>>(bi_rows, bi_cols, nbi, au,
                                           pa, paT, M_A, M_A);
  // pb = C1*u ^ C2*pa  (only the rows the output needs)
  k_ext<<<dim3(PB_USED / 4), 256, 0, stream>>>(c1_rows, c1_cols, nc1,
                                               c2_rows, c2_cols, nc2,
                                               u_pack, pa, pbT);
  k_out<<<dim3((N_OUT / 4 + 255) / 256, BATCH), 256, 0, stream>>>(uT, paT, pbT,
                                                                  out_int, out);
}

// Round 3
// 235.559 us; speedup vs baseline: 1.0508x; 1.0508x over previous
//
#include <hip/hip_runtime.h>
#include <stdint.h>

// ---------------- 5G LDPC BG1 encoder, bit-packed GF(2) pipeline (v3) ----------------
#define Zc      384
#define K_INFO  8000
#define N_OUT   16000
#define K_LDPC  8448        // 22*Z
#define M_A     1536        // 4*Z core parity
#define PB_USED 7232        // pb rows >= 7232 never reach the rate-matched output
#define WPR     64          // uint32 words per packed row (2048 batch bits)
#define BATCH   2048

typedef float f4v __attribute__((ext_vector_type(4)));
typedef unsigned int u32;

// Workspace layout (bytes, 256-aligned):
#define OFF_UPACK 0          // [8448][64] u32 row-major
#define OFF_UT    2162688    // [64][8448] u32 word-major (bit-planes)
#define OFF_PA    4325376    // [1536][64] u32 row-major
#define OFF_PAT   4718592    // [64][1536] u32 word-major
#define OFF_PBT   5111808    // [64][7232] u32 word-major
#define OFF_RPA   6963200    // int[1537]
#define OFF_RPBI  6969600    // int[1537]
#define OFF_RPC1  6976000    // int[7233]
#define OFF_RPC2  7005184    // int[7233]  (end ~7.04 MB)

__device__ __forceinline__ int lb(const int* __restrict__ a, int n, int key) {
  int lo = 0, hi = n;
  while (lo < hi) {
    int mid = (lo + hi) >> 1;
    if (a[mid] < key) lo = mid + 1; else hi = mid;
  }
  return lo;
}

// K0: row-pointer precompute — removes dependent binary-search chains from the
// hot parity kernels.
__global__ __launch_bounds__(256) void k_rowptr(
    const int* __restrict__ a_rows, int na,
    const int* __restrict__ bi_rows, int nbi,
    const int* __restrict__ c1_rows, int nc1,
    const int* __restrict__ c2_rows, int nc2,
    int* __restrict__ rp_a, int* __restrict__ rp_bi,
    int* __restrict__ rp_c1, int* __restrict__ rp_c2) {
  const int i = blockIdx.x * 256 + threadIdx.x;
  if (i <= M_A)     { rp_a[i]  = lb(a_rows,  na,  i); rp_bi[i] = lb(bi_rows, nbi, i); }
  if (i <= PB_USED) { rp_c1[i] = lb(c1_rows, nc1, i); rp_c2[i] = lb(c2_rows, nc2, i); }
}

// K1: pack u (float 0/1, [2048][8000]) into bit-planes. 64x64 tile via LDS +
// __ballot (wave=64). Filler rows 8000..8447 are written as zeros.
__global__ __launch_bounds__(256) void k_pack(const float* __restrict__ u,
                                              u32* __restrict__ u_pack,
                                              u32* __restrict__ uT) {
  __shared__ float tile[64][65];      // [batch][bit], padded
  __shared__ uint64_t bw[64];
  const int k0 = blockIdx.x * 64;
  const int b0 = blockIdx.y * 64;
  const int tid = threadIdx.x;

  #pragma unroll
  for (int i = 0; i < 4; ++i) {       // 64 rows x 16 float4 per tile
    int idx = tid + i * 256;
    int bb = idx >> 4, f4i = idx & 15;
    int k = k0 + f4i * 4;
    f4v v = (f4v)0.0f;
    if (k + 3 < K_INFO)               // K_INFO%64==0 -> never straddles
      v = __builtin_nontemporal_load(
            (const f4v*)(u + (size_t)(b0 + bb) * K_INFO + k));
    tile[bb][f4i*4+0] = v.x; tile[bb][f4i*4+1] = v.y;
    tile[bb][f4i*4+2] = v.z; tile[bb][f4i*4+3] = v.w;
  }
  __syncthreads();

  const int lane = tid & 63;
  const int wv   = tid >> 6;
  #pragma unroll
  for (int kk = 0; kk < 16; ++kk) {
    int kp = wv * 16 + kk;
    uint64_t m = __ballot(tile[lane][kp] != 0.0f);  // bit i = batch b0+i
    if (lane == 0) bw[kp] = m;
  }
  __syncthreads();

  if (tid < 64) {
    int row = k0 + tid;
    ((uint64_t*)(u_pack + (size_t)row * WPR))[blockIdx.y] = bw[tid];
  }
  if (tid < 128) {
    int half = tid >> 6, kk = tid & 63;
    uT[(size_t)(2 * blockIdx.y + half) * K_LDPC + k0 + kk] =
        (u32)(bw[kk] >> (32 * half));
  }
}

// K2: core parity fused: pa[r] = XOR_{e in Binv(r)} XOR_{e2 in A(j)} u_pack[...].
// One wave per lifted row; lane = batch word; 256B coalesced row gathers.
__global__ __launch_bounds__(256) void k_core(
    const int* __restrict__ a_cols,  const int* __restrict__ rp_a,
    const int* __restrict__ bi_cols, const int* __restrict__ rp_bi,
    const u32* __restrict__ u_pack,
    u32* __restrict__ pa, u32* __restrict__ paT) {
  const int r = blockIdx.x * 4 + (threadIdx.x >> 6);
  const int lane = threadIdx.x & 63;
  u32 acc = 0;
  const int lo = rp_bi[r], hi = rp_bi[r + 1];
  for (int e = lo; e < hi; ++e) {
    const int j = bi_cols[e];
    const int lo2 = rp_a[j], hi2 = rp_a[j + 1];
    for (int e2 = lo2; e2 < hi2; ++e2)
      acc ^= u_pack[(size_t)a_cols[e2] * WPR + lane];
  }
  pa[(size_t)r * WPR + lane] = acc;            // row-major (for C2 gathers)
  paT[(size_t)lane * M_A + r] = acc;           // word-major (for k_out)
}

// K3: extension parity rows 0..PB_USED-1: pb = C1*u ^ C2*pa.
__global__ __launch_bounds__(256) void k_ext(
    const int* __restrict__ c1_cols, const int* __restrict__ rp_c1,
    const int* __restrict__ c2_cols, const int* __restrict__ rp_c2,
    const u32* __restrict__ u_pack, const u32* __restrict__ pa,
    u32* __restrict__ pbT) {
  const int r = blockIdx.x * 4 + (threadIdx.x >> 6);
  const int lane = threadIdx.x & 63;
  u32 acc = 0;
  int lo = rp_c1[r], hi = rp_c1[r + 1];
  for (int e = lo; e < hi; ++e)
    acc ^= u_pack[(size_t)c1_cols[e] * WPR + lane];
  lo = rp_c2[r]; hi = rp_c2[r + 1];
  for (int e = lo; e < hi; ++e)
    acc ^= pa[(size_t)c2_cols[e] * WPR + lane];
  pbT[(size_t)lane * PB_USED + r] = acc;       // scattered 4B, 1.85MB total
}

// K4: output. Block = (t-range, word-plane w). Each thread loads its 4 plane
// words ONCE and emits all 32 batches of that word (bit = b&31) as nontemporal
// float4 stores. out[b][4t+j] = c_nf[768 + out_int[4t+j]][b]; region decode:
// row<8000 -> uT; row<9536 -> paT(row-8000); else pbT(row-9536).
__global__ __launch_bounds__(256) void k_out(const u32* __restrict__ uT,
                                             const u32* __restrict__ paT,
                                             const u32* __restrict__ pbT,
                                             const int* __restrict__ out_int,
                                             float* __restrict__ out) {
  const int t = blockIdx.x * 256 + threadIdx.x;
  if (t >= N_OUT / 4) return;
  const int w = blockIdx.y;                    // 0..63

  const int4 oi = *(const int4*)(out_int + 4 * t);
  const int rr[4] = {oi.x + 768, oi.y + 768, oi.z + 768, oi.w + 768};
  u32 wd[4];
  #pragma unroll
  for (int j = 0; j < 4; ++j) {
    const int row = rr[j];
    u32 v;
    if (row < 8000)      v = uT [(size_t)w * K_LDPC  + row];
    else if (row < 9536) v = paT[(size_t)w * M_A     + row - 8000];
    else                 v = pbT[(size_t)w * PB_USED + row - 9536];
    wd[j] = v;
  }

  float* op = out + (size_t)(w * 32) * N_OUT + 4 * t;
  #pragma unroll
  for (int bit = 0; bit < 32; ++bit) {
    f4v o;
    o.x = (float)((wd[0] >> bit) & 1u);
    o.y = (float)((wd[1] >> bit) & 1u);
    o.z = (float)((wd[2] >> bit) & 1u);
    o.w = (float)((wd[3] >> bit) & 1u);
    __builtin_nontemporal_store(o, (f4v*)(op + (size_t)bit * N_OUT));
  }
}

extern "C" void kernel_launch(void* const* d_in, const int* in_sizes, int n_in,
                              void* d_out, int out_size, void* d_ws, size_t ws_size,
                              hipStream_t stream) {
  const float* u      = (const float*)d_in[0];
  const int* a_rows   = (const int*)d_in[1];
  const int* a_cols   = (const int*)d_in[2];
  const int* bi_rows  = (const int*)d_in[3];
  const int* bi_cols  = (const int*)d_in[4];
  const int* c1_rows  = (const int*)d_in[5];
  const int* c1_cols  = (const int*)d_in[6];
  const int* c2_rows  = (const int*)d_in[7];
  const int* c2_cols  = (const int*)d_in[8];
  const int* out_int  = (const int*)d_in[9];
  const int na  = in_sizes[1];
  const int nbi = in_sizes[3];
  const int nc1 = in_sizes[5];
  const int nc2 = in_sizes[7];

  char* ws = (char*)d_ws;
  u32* u_pack = (u32*)(ws + OFF_UPACK);
  u32* uT     = (u32*)(ws + OFF_UT);
  u32* pa     = (u32*)(ws + OFF_PA);
  u32* paT    = (u32*)(ws + OFF_PAT);
  u32* pbT    = (u32*)(ws + OFF_PBT);
  int* rp_a   = (int*)(ws + OFF_RPA);
  int* rp_bi  = (int*)(ws + OFF_RPBI);
  int* rp_c1  = (int*)(ws + OFF_RPC1);
  int* rp_c2  = (int*)(ws + OFF_RPC2);
  float* out = (float*)d_out;

  k_rowptr<<<dim3((PB_USED + 256) / 256), 256, 0, stream>>>(
      a_rows, na, bi_rows, nbi, c1_rows, nc1, c2_rows, nc2,
      rp_a, rp_bi, rp_c1, rp_c2);
  k_pack<<<dim3(K_LDPC / 64, BATCH / 64), 256, 0, stream>>>(u, u_pack, uT);
  k_core<<<dim3(M_A / 4), 256, 0, stream>>>(a_cols, rp_a, bi_cols, rp_bi,
                                            u_pack, pa, paT);
  k_ext<<<dim3(PB_USED / 4), 256, 0, stream>>>(c1_cols, rp_c1, c2_cols, rp_c2,
                                               u_pack, pa, pbT);
  k_out<<<dim3((N_OUT / 4 + 255) / 256, WPR), 256, 0, stream>>>(uT, paT, pbT,
                                                                out_int, out);
}

// Round 5
// 232.806 us; speedup vs baseline: 1.0633x; 1.0118x over previous
//
#include <hip/hip_runtime.h>
#include <stdint.h>

// ------------- 5G LDPC BG1 encoder, bit-packed GF(2) pipeline (v4: 3 kernels) -------------
#define Zc      384
#define K_INFO  8000
#define N_OUT   16000
#define K_LDPC  8448        // 22*Z
#define M_A     1536        // 4*Z core parity
#define PB_USED 7232        // pb rows >= 7232 never reach the rate-matched output
#define WPR     64          // uint32 words per packed row (2048 batch bits)
#define BATCH   2048
#define PACK_TX 132         // k-tiles in k_pack grid.x (8448/64)
#define RP_BX   29          // extra grid.x blocks doing rowptr precompute

typedef float f4v __attribute__((ext_vector_type(4)));
typedef unsigned int u32;

// Workspace layout (bytes, 256-aligned):
#define OFF_UPACK 0          // [8448][64] u32 row-major
#define OFF_UT    2162688    // [64][8448] u32 word-major (bit-planes)
#define OFF_PAT   4325376    // [64][1536] u32 word-major
#define OFF_PBT   4718592    // [64][7232] u32 word-major
#define OFF_RPA   6569984    // int[1537]
#define OFF_RPBI  6576384    // int[1537]
#define OFF_RPC1  6582784    // int[7233]
#define OFF_RPC2  6611968    // int[7233]   (end ~6.64 MB)

__device__ __forceinline__ int lb(const int* __restrict__ a, int n, int key) {
  int lo = 0, hi = n;
  while (lo < hi) {
    int mid = (lo + hi) >> 1;
    if (a[mid] < key) lo = mid + 1; else hi = mid;
  }
  return lo;
}

// K1: pack u (float 0/1, [2048][8000]) into bit-planes (64x64 LDS tile +
// __ballot). Filler rows 8000..8447 written as zeros. Grid-x blocks >= PACK_TX
// (y==0 only) instead compute the CSR row pointers for the parity kernel —
// independent work overlapped with packing.
__global__ __launch_bounds__(256) void k_pack(const float* __restrict__ u,
                                              u32* __restrict__ u_pack,
                                              u32* __restrict__ uT,
                                              const int* __restrict__ a_rows, int na,
                                              const int* __restrict__ bi_rows, int nbi,
                                              const int* __restrict__ c1_rows, int nc1,
                                              const int* __restrict__ c2_rows, int nc2,
                                              int* __restrict__ rp_a,
                                              int* __restrict__ rp_bi,
                                              int* __restrict__ rp_c1,
                                              int* __restrict__ rp_c2) {
  const int tid = threadIdx.x;
  if (blockIdx.x >= PACK_TX) {              // rowptr blocks
    if (blockIdx.y != 0) return;
    const int i = (blockIdx.x - PACK_TX) * 256 + tid;
    if (i <= M_A)     { rp_a[i]  = lb(a_rows,  na,  i); rp_bi[i] = lb(bi_rows, nbi, i); }
    if (i <= PB_USED) { rp_c1[i] = lb(c1_rows, nc1, i); rp_c2[i] = lb(c2_rows, nc2, i); }
    return;
  }

  __shared__ float tile[64][65];            // [batch][bit], padded
  __shared__ uint64_t bw[64];
  const int k0 = blockIdx.x * 64;
  const int b0 = blockIdx.y * 64;

  #pragma unroll
  for (int i = 0; i < 4; ++i) {             // 64 rows x 16 float4 per tile
    int idx = tid + i * 256;
    int bb = idx >> 4, f4i = idx & 15;
    int k = k0 + f4i * 4;
    f4v v = (f4v)0.0f;
    if (k + 3 < K_INFO)                     // K_INFO%64==0 -> never straddles
      v = __builtin_nontemporal_load(
            (const f4v*)(u + (size_t)(b0 + bb) * K_INFO + k));
    tile[bb][f4i*4+0] = v.x; tile[bb][f4i*4+1] = v.y;
    tile[bb][f4i*4+2] = v.z; tile[bb][f4i*4+3] = v.w;
  }
  __syncthreads();

  const int lane = tid & 63;
  const int wv   = tid >> 6;
  #pragma unroll
  for (int kk = 0; kk < 16; ++kk) {
    int kp = wv * 16 + kk;
    uint64_t m = __ballot(tile[lane][kp] != 0.0f);  // bit i = batch b0+i
    if (lane == 0) bw[kp] = m;
  }
  __syncthreads();

  if (tid < 64) {
    int row = k0 + tid;
    ((uint64_t*)(u_pack + (size_t)row * WPR))[blockIdx.y] = bw[tid];
  }
  if (tid < 128) {
    int half = tid >> 6, kk = tid & 63;
    uT[(size_t)(2 * blockIdx.y + half) * K_LDPC + k0 + kk] =
        (u32)(bw[kk] >> (32 * half));
  }
}

// K2: all parity, fused. Blocks 0..383: pa rows (paT only, nested Binv*A
// gather). Blocks 384..: pb rows 0..7231 — recompute the ~1.75 pa rows each
// needs on the fly (L2-resident), removing the core->ext dependency.
// One wave per row; lane = batch word; 256B coalesced row gathers.
__global__ __launch_bounds__(256) void k_parity(
    const int* __restrict__ a_cols,  const int* __restrict__ rp_a,
    const int* __restrict__ bi_cols, const int* __restrict__ rp_bi,
    const int* __restrict__ c1_cols, const int* __restrict__ rp_c1,
    const int* __restrict__ c2_cols, const int* __restrict__ rp_c2,
    const u32* __restrict__ u_pack,
    u32* __restrict__ paT, u32* __restrict__ pbT) {
  const int lane = threadIdx.x & 63;
  const int wv   = threadIdx.x >> 6;
  const int bx = blockIdx.x;

  if (bx < M_A / 4) {                       // core parity: pa = B^-1 (A u)
    const int r = bx * 4 + wv;
    u32 acc = 0;
    const int lo = rp_bi[r], hi = rp_bi[r + 1];
    for (int e = lo; e < hi; ++e) {
      const int j = bi_cols[e];
      const int lo2 = rp_a[j], hi2 = rp_a[j + 1];
      for (int e2 = lo2; e2 < hi2; ++e2)
        acc ^= u_pack[(size_t)a_cols[e2] * WPR + lane];
    }
    paT[(size_t)lane * M_A + r] = acc;      // word-major for k_out
  } else {                                  // extension parity: pb = C1 u ^ C2 pa
    const int r = (bx - M_A / 4) * 4 + wv;
    if (r >= PB_USED) return;
    u32 acc = 0;
    int lo = rp_c1[r], hi = rp_c1[r + 1];
    for (int e = lo; e < hi; ++e)
      acc ^= u_pack[(size_t)c1_cols[e] * WPR + lane];
    lo = rp_c2[r]; hi = rp_c2[r + 1];
    for (int e = lo; e < hi; ++e) {         // on-the-fly pa recompute
      const int p = c2_cols[e];
      const int lo2 = rp_bi[p], hi2 = rp_bi[p + 1];
      for (int e2 = lo2; e2 < hi2; ++e2) {
        const int j = bi_cols[e2];
        const int lo3 = rp_a[j], hi3 = rp_a[j + 1];
        for (int e3 = lo3; e3 < hi3; ++e3)
          acc ^= u_pack[(size_t)a_cols[e3] * WPR + lane];
      }
    }
    pbT[(size_t)lane * PB_USED + r] = acc;
  }
}

// K3: output. Block = (t-range, word-plane w). Each thread loads its 4 plane
// words ONCE and emits all 32 batches of that word as nontemporal float4
// stores. out[b][4t+j] = c_nf[768 + out_int[4t+j]][b]; region decode:
// row<8000 -> uT; row<9536 -> paT(row-8000); else pbT(row-9536).
__global__ __launch_bounds__(256) void k_out(const u32* __restrict__ uT,
                                             const u32* __restrict__ paT,
                                             const u32* __restrict__ pbT,
                                             const int* __restrict__ out_int,
                                             float* __restrict__ out) {
  const int t = blockIdx.x * 256 + threadIdx.x;
  if (t >= N_OUT / 4) return;
  const int w = blockIdx.y;                 // 0..63

  const int4 oi = *(const int4*)(out_int + 4 * t);
  const int rr[4] = {oi.x + 768, oi.y + 768, oi.z + 768, oi.w + 768};
  u32 wd[4];
  #pragma unroll
  for (int j = 0; j < 4; ++j) {
    const int row = rr[j];
    u32 v;
    if (row < 8000)      v = uT [(size_t)w * K_LDPC  + row];
    else if (row < 9536) v = paT[(size_t)w * M_A     + row - 8000];
    else                 v = pbT[(size_t)w * PB_USED + row - 9536];
    wd[j] = v;
  }

  float* op = out + (size_t)(w * 32) * N_OUT + 4 * t;
  #pragma unroll
  for (int bit = 0; bit < 32; ++bit) {
    f4v o;
    o.x = (float)((wd[0] >> bit) & 1u);
    o.y = (float)((wd[1] >> bit) & 1u);
    o.z = (float)((wd[2] >> bit) & 1u);
    o.w = (float)((wd[3] >> bit) & 1u);
    __builtin_nontemporal_store(o, (f4v*)(op + (size_t)bit * N_OUT));
  }
}

extern "C" void kernel_launch(void* const* d_in, const int* in_sizes, int n_in,
                              void* d_out, int out_size, void* d_ws, size_t ws_size,
                              hipStream_t stream) {
  const float* u      = (const float*)d_in[0];
  const int* a_rows   = (const int*)d_in[1];
  const int* a_cols   = (const int*)d_in[2];
  const int* bi_rows  = (const int*)d_in[3];
  const int* bi_cols  = (const int*)d_in[4];
  const int* c1_rows  = (const int*)d_in[5];
  const int* c1_cols  = (const int*)d_in[6];
  const int* c2_rows  = (const int*)d_in[7];
  const int* c2_cols  = (const int*)d_in[8];
  const int* out_int  = (const int*)d_in[9];
  const int na  = in_sizes[1];
  const int nbi = in_sizes[3];
  const int nc1 = in_sizes[5];
  const int nc2 = in_sizes[7];

  char* ws = (char*)d_ws;
  u32* u_pack = (u32*)(ws + OFF_UPACK);
  u32* uT     = (u32*)(ws + OFF_UT);
  u32* paT    = (u32*)(ws + OFF_PAT);
  u32* pbT    = (u32*)(ws + OFF_PBT);
  int* rp_a   = (int*)(ws + OFF_RPA);
  int* rp_bi  = (int*)(ws + OFF_RPBI);
  int* rp_c1  = (int*)(ws + OFF_RPC1);
  int* rp_c2  = (int*)(ws + OFF_RPC2);
  float* out = (float*)d_out;

  k_pack<<<dim3(PACK_TX + RP_BX, BATCH / 64), 256, 0, stream>>>(
      u, u_pack, uT, a_rows, na, bi_rows, nbi, c1_rows, nc1, c2_rows, nc2,
      rp_a, rp_bi, rp_c1, rp_c2);
  k_parity<<<dim3(M_A / 4 + PB_USED / 4), 256, 0, stream>>>(
      a_cols, rp_a, bi_cols, rp_bi, c1_cols, rp_c1, c2_cols, rp_c2,
      u_pack, paT, pbT);
  k_out<<<dim3((N_OUT / 4 + 255) / 256, WPR), 256, 0, stream>>>(uT, paT, pbT,
                                                                out_int, out);
}

// Round 9
// 230.701 us; speedup vs baseline: 1.0730x; 1.0091x over previous
//
#include <hip/hip_runtime.h>
#include <stdint.h>

// ------------- 5G LDPC BG1 encoder, bit-packed GF(2) pipeline (v5b: 4 kernels) -------------
#define Zc      384
#define K_INFO  8000
#define N_OUT   16000
#define K_LDPC  8448        // 22*Z
#define M_A     1536        // 4*Z core parity
#define PB_USED 7232        // pb rows >= 7232 never reach the rate-matched output
#define WPR     64          // uint32 words per packed row (2048 batch bits)
#define BATCH   2048
#define PACK_TX 132         // k-tiles in k_pack grid.x (8448/64)
#define RP_BX   29          // extra grid.x blocks doing rowptr precompute

typedef float f4v __attribute__((ext_vector_type(4)));
typedef unsigned int u32;
typedef u32 u4v __attribute__((ext_vector_type(4)));

// Workspace layout (bytes, 256-aligned):
#define OFF_UPACK 0          // [8448][64] u32 row-major
#define OFF_UT    2162688    // [64][8448] u32 word-major (bit-planes)
#define OFF_PA    4325376    // [1536][64] u32 row-major (for C2 gathers)
#define OFF_PAT   4718592    // [64][1536] u32 word-major (for k_out)
#define OFF_PBT   5111808    // [64][7232] u32 word-major
#define OFF_RPA   6963200    // int[1537]
#define OFF_RPBI  6969600    // int[1537]
#define OFF_RPC1  6976000    // int[7233]
#define OFF_RPC2  7005184    // int[7233]   (end ~7.03 MB; ws is 500 MiB)

__device__ __forceinline__ int lb(const int* __restrict__ a, int n, int key) {
  int lo = 0, hi = n;
  while (lo < hi) {
    int mid = (lo + hi) >> 1;
    if (a[mid] < key) lo = mid + 1; else hi = mid;
  }
  return lo;
}

// K1: pack u (float 0/1, [2048][8000]) into bit-planes (64x64 LDS tile +
// __ballot). Filler rows 8000..8447 written as zeros. Grid-x blocks >= PACK_TX
// (y==0 only) compute the CSR row pointers instead — independent work
// overlapped with the packing tiles.
__global__ __launch_bounds__(256) void k_pack(const float* __restrict__ u,
                                              u32* __restrict__ u_pack,
                                              u32* __restrict__ uT,
                                              const int* __restrict__ a_rows, int na,
                                              const int* __restrict__ bi_rows, int nbi,
                                              const int* __restrict__ c1_rows, int nc1,
                                              const int* __restrict__ c2_rows, int nc2,
                                              int* __restrict__ rp_a,
                                              int* __restrict__ rp_bi,
                                              int* __restrict__ rp_c1,
                                              int* __restrict__ rp_c2) {
  const int tid = threadIdx.x;
  if (blockIdx.x >= PACK_TX) {              // rowptr blocks
    if (blockIdx.y != 0) return;
    const int i = (blockIdx.x - PACK_TX) * 256 + tid;
    if (i <= M_A)     { rp_a[i]  = lb(a_rows,  na,  i); rp_bi[i] = lb(bi_rows, nbi, i); }
    if (i <= PB_USED) { rp_c1[i] = lb(c1_rows, nc1, i); rp_c2[i] = lb(c2_rows, nc2, i); }
    return;
  }

  __shared__ float tile[64][65];            // [batch][bit], padded
  __shared__ uint64_t bw[64];
  const int k0 = blockIdx.x * 64;
  const int b0 = blockIdx.y * 64;

  #pragma unroll
  for (int i = 0; i < 4; ++i) {             // 64 rows x 16 float4 per tile
    int idx = tid + i * 256;
    int bb = idx >> 4, f4i = idx & 15;
    int k = k0 + f4i * 4;
    f4v v = (f4v)0.0f;
    if (k + 3 < K_INFO)                     // K_INFO%64==0 -> never straddles
      v = __builtin_nontemporal_load(
            (const f4v*)(u + (size_t)(b0 + bb) * K_INFO + k));
    tile[bb][f4i*4+0] = v.x; tile[bb][f4i*4+1] = v.y;
    tile[bb][f4i*4+2] = v.z; tile[bb][f4i*4+3] = v.w;
  }
  __syncthreads();

  const int lane = tid & 63;
  const int wv   = tid >> 6;
  #pragma unroll
  for (int kk = 0; kk < 16; ++kk) {
    int kp = wv * 16 + kk;
    uint64_t m = __ballot(tile[lane][kp] != 0.0f);  // bit i = batch b0+i
    if (lane == 0) bw[kp] = m;
  }
  __syncthreads();

  if (tid < 64) {
    int row = k0 + tid;
    ((uint64_t*)(u_pack + (size_t)row * WPR))[blockIdx.y] = bw[tid];
  }
  if (tid < 128) {
    int half = tid >> 6, kk = tid & 63;
    uT[(size_t)(2 * blockIdx.y + half) * K_LDPC + k0 + kk] =
        (u32)(bw[kk] >> (32 * half));
  }
}

// K2: core parity pa = B^-1 (A u) via nested gather. One wave per lifted row;
// lane = batch word. Writes row-major (for K3's C2 gathers) + word-major (K4).
__global__ __launch_bounds__(256) void k_core(
    const int* __restrict__ a_cols,  const int* __restrict__ rp_a,
    const int* __restrict__ bi_cols, const int* __restrict__ rp_bi,
    const u32* __restrict__ u_pack,
    u32* __restrict__ pa, u32* __restrict__ paT) {
  const int r = blockIdx.x * 4 + (threadIdx.x >> 6);
  const int lane = threadIdx.x & 63;
  u32 acc = 0;
  const int lo = rp_bi[r], hi = rp_bi[r + 1];
  for (int e = lo; e < hi; ++e) {
    const int j = bi_cols[e];
    const int lo2 = rp_a[j], hi2 = rp_a[j + 1];
    for (int e2 = lo2; e2 < hi2; ++e2)
      acc ^= u_pack[(size_t)a_cols[e2] * WPR + lane];
  }
  pa[(size_t)r * WPR + lane] = acc;
  paT[(size_t)lane * M_A + r] = acc;
}

// K3: extension parity rows 0..PB_USED-1: pb = C1 u ^ C2 pa (direct pa reads).
__global__ __launch_bounds__(256) void k_ext(
    const int* __restrict__ c1_cols, const int* __restrict__ rp_c1,
    const int* __restrict__ c2_cols, const int* __restrict__ rp_c2,
    const u32* __restrict__ u_pack, const u32* __restrict__ pa,
    u32* __restrict__ pbT) {
  const int r = blockIdx.x * 4 + (threadIdx.x >> 6);
  const int lane = threadIdx.x & 63;
  if (r >= PB_USED) return;
  u32 acc = 0;
  int lo = rp_c1[r], hi = rp_c1[r + 1];
  for (int e = lo; e < hi; ++e)
    acc ^= u_pack[(size_t)c1_cols[e] * WPR + lane];
  lo = rp_c2[r]; hi = rp_c2[r + 1];
  for (int e = lo; e < hi; ++e)
    acc ^= pa[(size_t)c2_cols[e] * WPR + lane];
  pbT[(size_t)lane * PB_USED + r] = acc;
}

// K4: output. Block = (t-range, word-plane w). Each thread loads its 4 plane
// words ONCE and emits all 32 batches as nontemporal u4v stores; bit->float
// is a 2-op and+cndmask (0x3F800000 = 1.0f). out[b][4t+j] =
// c_nf[768+out_int[4t+j]][b]; row<8000 -> uT; row<9536 -> paT; else pbT.
__global__ __launch_bounds__(256) void k_out(const u32* __restrict__ uT,
                                             const u32* __restrict__ paT,
                                             const u32* __restrict__ pbT,
                                             const int* __restrict__ out_int,
                                             u32* __restrict__ out) {
  const int t = blockIdx.x * 256 + threadIdx.x;
  if (t >= N_OUT / 4) return;
  const int w = blockIdx.y;                 // 0..63

  const int4 oi = *(const int4*)(out_int + 4 * t);
  const int rr[4] = {oi.x + 768, oi.y + 768, oi.z + 768, oi.w + 768};
  u32 wd[4];
  #pragma unroll
  for (int j = 0; j < 4; ++j) {
    const int row = rr[j];
    u32 v;
    if (row < 8000)      v = uT [(size_t)w * K_LDPC  + row];
    else if (row < 9536) v = paT[(size_t)w * M_A     + row - 8000];
    else                 v = pbT[(size_t)w * PB_USED + row - 9536];
    wd[j] = v;
  }

  u32* op = out + (size_t)(w * 32) * N_OUT + 4 * t;
  #pragma unroll
  for (int bit = 0; bit < 32; ++bit) {
    const u32 m = 1u << bit;
    u4v o;
    o.x = (wd[0] & m) ? 0x3F800000u : 0u;
    o.y = (wd[1] & m) ? 0x3F800000u : 0u;
    o.z = (wd[2] & m) ? 0x3F800000u : 0u;
    o.w = (wd[3] & m) ? 0x3F800000u : 0u;
    __builtin_nontemporal_store(o, (u4v*)(op + (size_t)bit * N_OUT));
  }
}

extern "C" void kernel_launch(void* const* d_in, const int* in_sizes, int n_in,
                              void* d_out, int out_size, void* d_ws, size_t ws_size,
                              hipStream_t stream) {
  const float* u      = (const float*)d_in[0];
  const int* a_rows   = (const int*)d_in[1];
  const int* a_cols   = (const int*)d_in[2];
  const int* bi_rows  = (const int*)d_in[3];
  const int* bi_cols  = (const int*)d_in[4];
  const int* c1_rows  = (const int*)d_in[5];
  const int* c1_cols  = (const int*)d_in[6];
  const int* c2_rows  = (const int*)d_in[7];
  const int* c2_cols  = (const int*)d_in[8];
  const int* out_int  = (const int*)d_in[9];
  const int na  = in_sizes[1];
  const int nbi = in_sizes[3];
  const int nc1 = in_sizes[5];
  const int nc2 = in_sizes[7];

  char* ws = (char*)d_ws;
  u32* u_pack = (u32*)(ws + OFF_UPACK);
  u32* uT     = (u32*)(ws + OFF_UT);
  u32* pa     = (u32*)(ws + OFF_PA);
  u32* paT    = (u32*)(ws + OFF_PAT);
  u32* pbT    = (u32*)(ws + OFF_PBT);
  int* rp_a   = (int*)(ws + OFF_RPA);
  int* rp_bi  = (int*)(ws + OFF_RPBI);
  int* rp_c1  = (int*)(ws + OFF_RPC1);
  int* rp_c2  = (int*)(ws + OFF_RPC2);

  k_pack<<<dim3(PACK_TX + RP_BX, BATCH / 64), 256, 0, stream>>>(
      u, u_pack, uT, a_rows, na, bi_rows, nbi, c1_rows, nc1, c2_rows, nc2,
      rp_a, rp_bi, rp_c1, rp_c2);
  k_core<<<dim3(M_A / 4), 256, 0, stream>>>(a_cols, rp_a, bi_cols, rp_bi,
                                            u_pack, pa, paT);
  k_ext<<<dim3(PB_USED / 4), 256, 0, stream>>>(c1_cols, rp_c1, c2_cols, rp_c2,
                                               u_pack, pa, pbT);
  k_out<<<dim3((N_OUT / 4 + 255) / 256, WPR), 256, 0, stream>>>(
      uT, paT, pbT, out_int, (u32*)d_out);
}